// Round 3
// baseline (189.594 us; speedup 1.0000x reference)
//
#include <hip/hip_runtime.h>
#include <cstdint>

// PassiveLayer muon scattering, fused single kernel.
// PRNG reproduces JAX threefry2x32 bit-exactly:
//   base key = (0, 42); step key_i = threefry((0,42), (0, i))
//   zr[0][n],zr[2][n] = threefry(key_i, (n, n+2N)) words 0,1
//   zr[1][n],zr[3][n] = threefry(key_i, (N+n, 3N+n)) words 0,1
//
// Numeric-risk policy (absmax 0.20224 vs threshold 0.2025, margin 0.13%):
//  - POSITION-critical ops (libm tanf, x/VSIZE voxel divide, rsqrtf->dz,
//    update expression shapes) identical to the passing R1-R4 kernels. DO NOT TOUCH.
//  - theta0/z-draw path (damped by ~0.0136) uses hw transcendentals; R2
//    proved ~1ulp perturbations there leave absmax bit-stable.
//  - R5, both transformations BIT-EXACT by construction:
//    (a) per-voxel {S=sqrt(n_x0), F=fmaf(B,log(n_x0),1), x0} table precomputed
//        on device with the IDENTICAL intrinsic sequence; fast path
//        theta0 = (cop*S)*F keeps the original association -> same bits.
//        Wave-uniform fast/slow split: slow path is the verbatim original
//        chain (runs only on the partial/final iterations).
//    (b) tan carry: prologue tan == iteration-0 tan; end-of-body tan ==
//        epilogue tan. Same inputs to the same libm call -> same bits.

constexpr int   NSTEPS = 32;
constexpr float Z_TOP  = 1.0f;
constexpr float Z_BOT  = 0.9f;
constexpr float LW     = 10.0f;
constexpr float VSIZE  = 0.1f;
constexpr float STEP   = 0.01f;
constexpr float COEF_A = 13.6e-3f;
constexpr float COEF_B = 0.038f;
constexpr int   NVOX   = 100 * 100;

__host__ __device__ constexpr uint32_t rotl32c(uint32_t v, int d) {
  return (v << d) | (v >> (32 - d));
}

// JAX threefry2x32 (20 rounds, 5 key injections) — constexpr-capable.
template <typename U>
__host__ __device__ constexpr void threefry2x32(U k0, U k1, U& x0, U& x1) {
  U k2 = k0 ^ k1 ^ 0x1BD11BDAu;
  x0 += k0; x1 += k1;
#define TF_R(r) { x0 += x1; x1 = rotl32c(x1, r); x1 ^= x0; }
  TF_R(13) TF_R(15) TF_R(26) TF_R(6)
  x0 += k1; x1 += k2 + 1u;
  TF_R(17) TF_R(29) TF_R(16) TF_R(24)
  x0 += k2; x1 += k0 + 2u;
  TF_R(13) TF_R(15) TF_R(26) TF_R(6)
  x0 += k0; x1 += k1 + 3u;
  TF_R(17) TF_R(29) TF_R(16) TF_R(24)
  x0 += k1; x1 += k2 + 4u;
  TF_R(13) TF_R(15) TF_R(26) TF_R(6)
  x0 += k2; x1 += k0 + 5u;
#undef TF_R
}

// Per-step keys: fold_in(key(42), i) = threefry((0,42), (0,i)) — compile-time.
struct KeyTab { uint32_t a[NSTEPS]; uint32_t b[NSTEPS]; };
constexpr KeyTab make_keys() {
  KeyTab t{};
  for (int i = 0; i < NSTEPS; ++i) {
    uint32_t x0 = 0u, x1 = (uint32_t)i;
    threefry2x32(0u, 42u, x0, x1);
    t.a[i] = x0; t.b[i] = x1;
  }
  return t;
}
__device__ __constant__ KeyTab SKEYS = make_keys();

// bits -> uniform u in [nextafter(-1,0), 1)  (bit-identical to jax mapping)
__device__ __forceinline__ float bits_to_uniform(uint32_t bits) {
  uint32_t fb = (bits >> 9) | 0x3f800000u;
  float f = __uint_as_float(fb) - 1.0f;        // [0, 1)
  const float lo = -0.99999994f;               // nextafter(-1,0)
  float u = f * 2.0f + lo;
  return fmaxf(lo, u);
}

// XLA ErfInv chain-1 polynomial with sqrt(2) pre-folded into coefficients.
__device__ __forceinline__ float erfinv_p1_s2(float w) {
  float ws = w - 2.5f;
  float p = 3.9742775e-08f;
  p = fmaf(p, ws, 4.8546373e-07f);
  p = fmaf(p, ws, -4.9828418e-06f);
  p = fmaf(p, ws, -6.2105426e-06f);
  p = fmaf(p, ws, 3.0912074e-04f);
  p = fmaf(p, ws, -1.7730442e-03f);
  p = fmaf(p, ws, -5.9081479e-03f);
  p = fmaf(p, ws, 3.4880632e-01f);
  p = fmaf(p, ws, 2.1233167e+00f);
  return p;
}
// chain-2 (w >= 5), sqrt(2)-folded
__device__ __forceinline__ float erfinv_p2_s2(float w) {
  float wb = __builtin_amdgcn_sqrtf(w) - 3.0f;
  float p = -2.8314768e-04f;
  p = fmaf(p, wb, 1.4276574e-04f);
  p = fmaf(p, wb, 1.9082629e-03f);
  p = fmaf(p, wb, -5.1950087e-03f);
  p = fmaf(p, wb, 8.1169428e-03f);
  p = fmaf(p, wb, -1.0779867e-02f);
  p = fmaf(p, wb, 1.3348557e-02f);
  p = fmaf(p, wb, 1.4165801e+00f);
  p = fmaf(p, wb, 4.0060855e+00f);
  return p;
}

// Per-voxel precompute for the FULL-step (step_len == STEP) theta0 sub-chain.
// EXACT replication of the main kernel's ops: n = STEP*rcp(x0);
// S = sqrt(n); F = fmaf(B, log(n), 1). Stored {S, F, x0, 0}.
__global__ __launch_bounds__(256)
void prep_tab_kernel(const float* __restrict__ rad, float4* __restrict__ tab,
                     int nvox) {
  int v = blockIdx.x * blockDim.x + threadIdx.x;
  if (v >= nvox) return;
  float x0 = rad[v];
  float n_x0 = STEP * __builtin_amdgcn_rcpf(x0);
  float S = __builtin_amdgcn_sqrtf(n_x0);
  float F = fmaf(COEF_B, __logf(n_x0), 1.0f);
  tab[v] = make_float4(S, F, x0, 0.0f);
}

template <bool USE_TAB>
__global__ __launch_bounds__(256)
void passive_layer_kernel(const float* __restrict__ xin,
                          const float* __restrict__ yin,
                          const float* __restrict__ zin,
                          const float* __restrict__ txin,
                          const float* __restrict__ tyin,
                          const float* __restrict__ momin,
                          const float* __restrict__ rad,
                          const float4* __restrict__ tab,
                          float* __restrict__ out, int N) {
  int n = blockIdx.x * blockDim.x + threadIdx.x;
  if (n >= N) return;

  float x = xin[n], y = yin[n], z = zin[n];
  float tx = txin[n], ty = tyin[n];
  float coef_over_p = COEF_A / momin[n];
  const uint32_t uN = (uint32_t)N;
  const uint32_t un = (uint32_t)n;
  const uint32_t c0a = un,      c1a = un + 2u * uN;
  const uint32_t c0b = un + uN, c1b = un + 3u * uN;

  // propagate to top of layer (position-critical: libm tanf).
  // ttx/tty are carried: prologue value == iteration-0 value (same tx).
  float ttx = tanf(tx), tty = tanf(ty);
  float dz0 = z - Z_TOP;
  x += dz0 * ttx;
  y += dz0 * tty;
  z -= dz0;

#pragma unroll 1
  for (int i = 0; i < NSTEPS; ++i) {
    bool mask = (z > Z_BOT) && (z <= Z_TOP);
    // BIT-EXACT early exit: once z==Z_BOT (exact snap), the lane's body is a
    // no-op forever; when no lane is alive the rest of the loop does nothing.
    if (!__any(mask)) break;

    // Scattered gather first so latency hides under threefry/erfinv work.
    bool smask = (x >= 0.0f) && (x < LW) && (y >= 0.0f) && (y < LW) && mask;
    int ix = (int)floorf(x / VSIZE); ix = min(max(ix, 0), 99);  // exact divide
    int iy = (int)floorf(y / VSIZE); iy = min(max(iy, 0), 99);
    int vidx = ix * 100 + iy;
    float4 t4;
    float x0s;
    if constexpr (USE_TAB) { t4 = tab[vidx]; } else { x0s = rad[vidx]; }

    uint32_t k0 = SKEYS.a[i], k1 = SKEYS.b[i];   // wave-uniform scalar loads
    uint32_t a0 = c0a, a1 = c1a;
    threefry2x32(k0, k1, a0, a1);            // -> zr0, zr2
    uint32_t b0 = c0b, b1 = c1b;
    threefry2x32(k0, k1, b0, b1);            // -> zr1, zr3

    float s = 1.0f + ttx * ttx + tty * tty;  // ttx/tty carried (same bits)
    float cos_th = rsqrtf(s);                // position-critical (dz)

    // theta0 path (damped). Fast path when every ALIVE lane takes a full
    // step (r_out >= STEP): step_len == STEP exactly, so theta0 = (cop*S)*F
    // with precomputed S,F is BIT-IDENTICAL to the original chain.
    float r_out = (z - Z_BOT) * __builtin_amdgcn_sqrtf(s);
    float step_len, theta0;
    if constexpr (USE_TAB) {
      bool lane_slow = mask && (r_out < STEP);
      if (!__any(lane_slow)) {               // ~10 of ~12 iterations
        step_len = STEP;
        theta0 = (coef_over_p * t4.x) * t4.y;
      } else {                               // verbatim original (partial/tail)
        step_len = fmaxf(fminf(STEP, r_out), 1e-9f);
        float n_x0 = step_len * __builtin_amdgcn_rcpf(t4.z);
        theta0 = (coef_over_p * __builtin_amdgcn_sqrtf(n_x0))
               * fmaf(COEF_B, __logf(n_x0), 1.0f);
      }
    } else {
      step_len = fmaxf(fminf(STEP, r_out), 1e-9f);
      float n_x0 = step_len * __builtin_amdgcn_rcpf(x0s);
      theta0 = (coef_over_p * __builtin_amdgcn_sqrtf(n_x0))
             * fmaf(COEF_B, __logf(n_x0), 1.0f);
    }

    // normals: u -> w -> poly; chain-2 only if some lane needs it (bit-exact)
    float u0 = bits_to_uniform(a0);
    float u1 = bits_to_uniform(b0);
    float u2 = bits_to_uniform(a1);
    float u3 = bits_to_uniform(b1);
    float w0 = -__logf(fmaf(u0, -u0, 1.0f));
    float w1 = -__logf(fmaf(u1, -u1, 1.0f));
    float w2 = -__logf(fmaf(u2, -u2, 1.0f));
    float w3 = -__logf(fmaf(u3, -u3, 1.0f));
    float p0 = erfinv_p1_s2(w0);
    float p1 = erfinv_p1_s2(w1);
    float p2 = erfinv_p1_s2(w2);
    float p3 = erfinv_p1_s2(w3);
    float wmax = fmaxf(fmaxf(w0, w1), fmaxf(w2, w3));
    if (__any(wmax >= 5.0f)) {               // ~58% of waves
      p0 = (w0 < 5.0f) ? p0 : erfinv_p2_s2(w0);
      p1 = (w1 < 5.0f) ? p1 : erfinv_p2_s2(w1);
      p2 = (w2 < 5.0f) ? p2 : erfinv_p2_s2(w2);
      p3 = (w3 < 5.0f) ? p3 : erfinv_p2_s2(w3);
    }
    float z0 = p0 * u0;                      // sqrt(2) already folded in
    float z1 = p1 * u1;
    float z2 = p2 * u2;
    float z3 = p3 * u3;

    float dtx = theta0 * z0;
    float dty = theta0 * z1;
    float slt = step_len * theta0;
    const float inv_s12 = 0.28867513459f;    // 1/sqrt(12), damped path
    float dxv = slt * (z2 * inv_s12 + z0 * 0.5f);
    float dyv = slt * (z3 * inv_s12 + z1 * 0.5f);

    // Position updates as selects on deltas — literally the reference
    // where()-formula; same expression shapes as R1-R4 (contraction-safe).
    float dxvm = smask ? dxv : 0.0f;
    float dyvm = smask ? dyv : 0.0f;
    x += dxvm;
    y += dyvm;

    float dz  = STEP * cos_th;
    float dzm = mask ? dz : 0.0f;
    x += dzm * ttx;
    y += dzm * tty;
    z -= dzm;

    float dzr  = z - Z_BOT;
    bool  em   = (dzr < 0.0f) && mask;
    float dzrm = em ? dzr : 0.0f;
    x += dzrm * ttx;
    y += dzrm * tty;
    z -= dzrm;

    float dtxm = smask ? dtx : 0.0f;
    float dtym = smask ? dty : 0.0f;
    tx += dtxm;
    ty += dtym;

    // tan for the NEXT iteration (and, on the last executed iteration, for
    // the epilogue): same libm call on the updated tx/ty -> same bits as the
    // original's recompute. Overlaps the back-edge/mask/gather/threefry.
    ttx = tanf(tx);
    tty = tanf(ty);
  }

  // snap to bottom of layer (ttx/tty == tanf(final tx/ty), bit-exact)
  float dz1 = z - Z_BOT;
  x += dz1 * ttx;
  y += dz1 * tty;

  float4 o = make_float4(x, y, tx, ty);
  reinterpret_cast<float4*>(out)[n] = o;
}

extern "C" void kernel_launch(void* const* d_in, const int* in_sizes, int n_in,
                              void* d_out, int out_size, void* d_ws, size_t ws_size,
                              hipStream_t stream) {
  const float* x   = (const float*)d_in[0];
  const float* y   = (const float*)d_in[1];
  const float* z   = (const float*)d_in[2];
  const float* tx  = (const float*)d_in[3];
  const float* ty  = (const float*)d_in[4];
  const float* mom = (const float*)d_in[5];
  const float* rad = (const float*)d_in[6];
  float* out = (float*)d_out;
  int N = in_sizes[0];
  int block = 256;
  int grid = (N + block - 1) / block;

  const size_t tab_bytes = (size_t)NVOX * sizeof(float4);
  if (d_ws != nullptr && ws_size >= tab_bytes) {
    float4* tab = (float4*)d_ws;
    int pgrid = (NVOX + block - 1) / block;
    prep_tab_kernel<<<pgrid, block, 0, stream>>>(rad, tab, NVOX);
    passive_layer_kernel<true><<<grid, block, 0, stream>>>(
        x, y, z, tx, ty, mom, rad, tab, out, N);
  } else {
    passive_layer_kernel<false><<<grid, block, 0, stream>>>(
        x, y, z, tx, ty, mom, rad, nullptr, out, N);
  }
}